// Round 3
// baseline (496.103 us; speedup 1.0000x reference)
//
#include <hip/hip_runtime.h>
#include <math.h>

#define BATCH 32
#define DIN   2048
#define DK    128
#define NREPS 400000
#define ACT   7
#define TROWS 64
#define NTILE (NREPS / TROWS)   /* 6250 tiles of 64 rows, exact */
#define STRIDE 132              /* padded LDS row stride (floats), 16B-aligned */
#define GDEF  694               /* ~9 iters/block, near-exact balance */

typedef __attribute__((ext_vector_type(8))) __bf16 bf16x8;
typedef __attribute__((ext_vector_type(4))) float  f32x4;

static __device__ __forceinline__ __bf16 bits2bf(unsigned short v) {
    union { unsigned short u; __bf16 b; } x; x.u = v; return x.b;
}

__device__ __forceinline__ void topk_insert(float s, int n,
    float& d0, float& d1, float& d2, float& d3, float& d4,
    int& i0, int& i1, int& i2, int& i3, int& i4)
{
    if (s < d4) {
        if (s < d3) {
            d4 = d3; i4 = i3;
            if (s < d2) {
                d3 = d2; i3 = i2;
                if (s < d1) {
                    d2 = d1; i2 = i1;
                    if (s < d0) { d1 = d0; i1 = i0; d0 = s; i0 = n; }
                    else        { d1 = s;  i1 = n; }
                } else { d2 = s; i2 = n; }
            } else { d3 = s; i3 = n; }
        } else { d4 = s; i4 = n; }
    }
}

// ---------------------------------------------------------------------------
// Kernel 1: batch_rep = x @ W_enc + b_enc. Writes brep_t[k][b] = -2*br[b][k]
// (k-major, pre-scaled) and brnorm[b] = ||br_b||^2.
// ---------------------------------------------------------------------------
__global__ __launch_bounds__(256) void encoder_kernel(
    const float* __restrict__ x, const float* __restrict__ W,
    const float* __restrict__ be, float* __restrict__ brept,
    float* __restrict__ brnorm)
{
    __shared__ float xs[DIN];
    __shared__ float part[256];
    __shared__ float vrow[DK];
    const int b = blockIdx.x, t = threadIdx.x;

    const float4* x4 = (const float4*)(x + (size_t)b * DIN);
    float4* xs4 = (float4*)xs;
    xs4[t]       = x4[t];
    xs4[t + 256] = x4[t + 256];
    __syncthreads();

    const int d = t & 127, h = t >> 7;
    const float* Wp = W + (size_t)(h * 1024) * DK + d;
    const float* xp = xs + h * 1024;
    float a0 = 0.f, a1 = 0.f, a2 = 0.f, a3 = 0.f;
    for (int i = 0; i < 1024; i += 4) {
        a0 = fmaf(xp[i],     Wp[(size_t)i * DK],       a0);
        a1 = fmaf(xp[i + 1], Wp[(size_t)(i + 1) * DK], a1);
        a2 = fmaf(xp[i + 2], Wp[(size_t)(i + 2) * DK], a2);
        a3 = fmaf(xp[i + 3], Wp[(size_t)(i + 3) * DK], a3);
    }
    part[t] = (a0 + a1) + (a2 + a3);
    __syncthreads();
    if (t < DK) {
        float v = part[t] + part[t + 128] + be[t];
        brept[t * BATCH + b] = -2.0f * v;
        vrow[t] = v * v;
    }
    __syncthreads();
    if (t == 0) {
        float s = 0.f;
        for (int i = 0; i < DK; i++) s += vrow[i];
        brnorm[b] = s;
    }
}

// ---------------------------------------------------------------------------
// Kernel 2: MFMA split-bf16 distance + per-lane top-5.
// Block stages 64 reps rows (fp32, stride-132 LDS, bank-balanced). Each of 4
// waves computes a 16n x 32b C-tile via mfma_f32_16x16x32_bf16 with hi/lo
// split (ah*bh + ah*bl + al*bh; rel err ~2^-16). B-frags (-2*brep) resident
// in regs. Next tile prefetched into regs during compute. Norms folded into
// staging via shfl. s = ||r||^2 - 2 br.r (+||br||^2 later).
// ---------------------------------------------------------------------------
__global__ __launch_bounds__(256, 2) void dist_topk_kernel(
    const float* __restrict__ reps, const float* __restrict__ brt,
    float* __restrict__ pd, int* __restrict__ pi)
{
    __shared__ float tile[TROWS * STRIDE];   // 33792 B
    __shared__ float nrmb[TROWS];
    const int t = threadIdx.x, g = blockIdx.x, G = gridDim.x;
    const int wv = t >> 6, ln = t & 63;
    const int c = ln & 15, quad = ln >> 4;
    const int srow = t >> 2, sq = t & 3;     // staging: row, quarter

    // ---- resident B-fragments: B[k = quad*8+j][n = b = nt*16+c], hi/lo
    bf16x8 Bh[2][4], Bl[2][4];
    #pragma unroll
    for (int nt = 0; nt < 2; nt++)
        #pragma unroll
        for (int ks = 0; ks < 4; ks++) {
            bf16x8 h, l;
            #pragma unroll
            for (int j = 0; j < 8; j++) {
                const float f = brt[(ks * 32 + quad * 8 + j) * BATCH + nt * 16 + c];
                const unsigned u = __float_as_uint(f);
                h[j] = bits2bf((unsigned short)(u >> 16));
                const float lf = f - __uint_as_float(u & 0xFFFF0000u);
                l[j] = bits2bf((unsigned short)(__float_as_uint(lf) >> 16));
            }
            Bh[nt][ks] = h; Bl[nt][ks] = l;
        }

    // ---- top-5 state: list 0 for b=c, list 1 for b=c+16
    float tA0 = 3.0e38f, tA1 = 3.0e38f, tA2 = 3.0e38f, tA3 = 3.0e38f, tA4 = 3.0e38f;
    int   jA0 = 0, jA1 = 0, jA2 = 0, jA3 = 0, jA4 = 0;
    float tB0 = 3.0e38f, tB1 = 3.0e38f, tB2 = 3.0e38f, tB3 = 3.0e38f, tB4 = 3.0e38f;
    int   jB0 = 0, jB1 = 0, jB2 = 0, jB3 = 0, jB4 = 0;

    // ---- prologue: stage tile g
    {
        const float4* gs = (const float4*)reps + (size_t)g * 2048 + srow * 32 + sq;
        float4 r[8];
        #pragma unroll
        for (int i = 0; i < 8; i++) r[i] = gs[4 * i];
        float s = 0.f;
        #pragma unroll
        for (int i = 0; i < 8; i++) {
            s = fmaf(r[i].x, r[i].x, s); s = fmaf(r[i].y, r[i].y, s);
            s = fmaf(r[i].z, r[i].z, s); s = fmaf(r[i].w, r[i].w, s);
        }
        s += __shfl_xor(s, 1); s += __shfl_xor(s, 2);
        #pragma unroll
        for (int i = 0; i < 8; i++)
            *(f32x4*)&tile[srow * STRIDE + (sq + 4 * i) * 4] =
                (f32x4){r[i].x, r[i].y, r[i].z, r[i].w};
        if ((t & 3) == 0) nrmb[srow] = s;
    }
    __syncthreads();

    int it = g;
    while (true) {
        const int itn = it + G;
        const bool have = itn < NTILE;
        float4 r[8];
        if (have) {  // prefetch next tile into regs (hides HBM latency)
            const float4* gs = (const float4*)reps + (size_t)itn * 2048 + srow * 32 + sq;
            #pragma unroll
            for (int i = 0; i < 8; i++) r[i] = gs[4 * i];
        }

        // ---- compute: 16n x 32b, k=128, 3 mfmas per (nt,ks) for hi/lo
        f32x4 C0 = {0.f, 0.f, 0.f, 0.f}, C1 = {0.f, 0.f, 0.f, 0.f};
        #pragma unroll
        for (int ks = 0; ks < 4; ks++) {
            const float* ap = &tile[(wv * 16 + c) * STRIDE + ks * 32 + quad * 8];
            const f32x4 a0 = *(const f32x4*)ap;
            const f32x4 a1 = *(const f32x4*)(ap + 4);
            bf16x8 ah, al;
            #pragma unroll
            for (int j = 0; j < 8; j++) {
                const float f = (j < 4) ? a0[j] : a1[j - 4];
                const unsigned u = __float_as_uint(f);
                ah[j] = bits2bf((unsigned short)(u >> 16));
                const float lf = f - __uint_as_float(u & 0xFFFF0000u);
                al[j] = bits2bf((unsigned short)(__float_as_uint(lf) >> 16));
            }
            C0 = __builtin_amdgcn_mfma_f32_16x16x32_bf16(ah, Bh[0][ks], C0, 0, 0, 0);
            C0 = __builtin_amdgcn_mfma_f32_16x16x32_bf16(ah, Bl[0][ks], C0, 0, 0, 0);
            C0 = __builtin_amdgcn_mfma_f32_16x16x32_bf16(al, Bh[0][ks], C0, 0, 0, 0);
            C1 = __builtin_amdgcn_mfma_f32_16x16x32_bf16(ah, Bh[1][ks], C1, 0, 0, 0);
            C1 = __builtin_amdgcn_mfma_f32_16x16x32_bf16(ah, Bl[1][ks], C1, 0, 0, 0);
            C1 = __builtin_amdgcn_mfma_f32_16x16x32_bf16(al, Bh[1][ks], C1, 0, 0, 0);
        }
        // ---- add rep norms, top-k. C/D: row n = quad*4+reg, col b = lane&15.
        {
            const int rowb = wv * 16 + quad * 4;
            const int nb = it * TROWS + rowb;
            #pragma unroll
            for (int reg = 0; reg < 4; reg++) {
                const float nr = nrmb[rowb + reg];
                const float s0 = C0[reg] + nr;
                const float s1 = C1[reg] + nr;
                topk_insert(s0, nb + reg, tA0, tA1, tA2, tA3, tA4, jA0, jA1, jA2, jA3, jA4);
                topk_insert(s1, nb + reg, tB0, tB1, tB2, tB3, tB4, jB0, jB1, jB2, jB3, jB4);
            }
        }
        __syncthreads();            // all waves done reading tile
        if (have) {
            float s = 0.f;
            #pragma unroll
            for (int i = 0; i < 8; i++) {
                s = fmaf(r[i].x, r[i].x, s); s = fmaf(r[i].y, r[i].y, s);
                s = fmaf(r[i].z, r[i].z, s); s = fmaf(r[i].w, r[i].w, s);
            }
            s += __shfl_xor(s, 1); s += __shfl_xor(s, 2);
            #pragma unroll
            for (int i = 0; i < 8; i++)
                *(f32x4*)&tile[srow * STRIDE + (sq + 4 * i) * 4] =
                    (f32x4){r[i].x, r[i].y, r[i].z, r[i].w};
            if ((t & 3) == 0) nrmb[srow] = s;
        }
        __syncthreads();
        if (!have) break;
        it = itn;
    }

    // ---- block merge: per b, 16 lists (4 waves x 4 quads). Reuse tile.
    float* cD = tile;                 // 2560 f
    int*   cI = (int*)(tile + 2560);  // 2560 i
    {
        const int base0 = ((0 * 16 + c) * 16 + (wv * 4 + quad)) * 5;
        cD[base0]     = tA0; cI[base0]     = jA0;
        cD[base0 + 1] = tA1; cI[base0 + 1] = jA1;
        cD[base0 + 2] = tA2; cI[base0 + 2] = jA2;
        cD[base0 + 3] = tA3; cI[base0 + 3] = jA3;
        cD[base0 + 4] = tA4; cI[base0 + 4] = jA4;
        const int base1 = ((16 + c) * 16 + (wv * 4 + quad)) * 5;
        cD[base1]     = tB0; cI[base1]     = jB0;
        cD[base1 + 1] = tB1; cI[base1 + 1] = jB1;
        cD[base1 + 2] = tB2; cI[base1 + 2] = jB2;
        cD[base1 + 3] = tB3; cI[base1 + 3] = jB3;
        cD[base1 + 4] = tB4; cI[base1 + 4] = jB4;
    }
    __syncthreads();
    if (t < 32) {
        float d0 = 3.0e38f, d1 = 3.0e38f, d2 = 3.0e38f, d3 = 3.0e38f, d4 = 3.0e38f;
        int   i0 = 0, i1 = 0, i2 = 0, i3 = 0, i4 = 0;
        for (int s2 = 0; s2 < 16; s2++) {
            const int base = (t * 16 + s2) * 5;
            #pragma unroll
            for (int e = 0; e < 5; e++)
                topk_insert(cD[base + e], cI[base + e],
                            d0, d1, d2, d3, d4, i0, i1, i2, i3, i4);
        }
        const int ob = (g * BATCH + t) * 5;
        pd[ob] = d0; pd[ob + 1] = d1; pd[ob + 2] = d2; pd[ob + 3] = d3; pd[ob + 4] = d4;
        pi[ob] = i0; pi[ob + 1] = i1; pi[ob + 2] = i2; pi[ob + 3] = i3; pi[ob + 4] = i4;
    }
}

// ---------------------------------------------------------------------------
// Kernel 3: merge G partial lists per b -> approx top-10 -> EXACT fp32
// distance recompute for the 10 candidates -> exact top-5 -> softmax ->
// weighted action average. Output is order-invariant, so no re-sort issues.
// ---------------------------------------------------------------------------
__global__ __launch_bounds__(256) void final_kernel(
    const float* __restrict__ pd, const int* __restrict__ pi,
    const float* __restrict__ brnorm, const float* __restrict__ actions,
    const float* __restrict__ reps, const float* __restrict__ brt,
    float* __restrict__ out, int G)
{
    __shared__ float lD[256 * 5];
    __shared__ int   lI[256 * 5];
    __shared__ float sD[32 * 5];
    __shared__ int   sI[32 * 5];
    __shared__ int   exi[10];
    __shared__ float exq[10];
    const int b = blockIdx.x, t = threadIdx.x;

    float d0 = 3.0e38f, d1 = 3.0e38f, d2 = 3.0e38f, d3 = 3.0e38f, d4 = 3.0e38f;
    int   i0 = 0, i1 = 0, i2 = 0, i3 = 0, i4 = 0;
    for (int g = t; g < G; g += 256) {
        const int base = (g * BATCH + b) * 5;
        #pragma unroll
        for (int e = 0; e < 5; e++)
            topk_insert(pd[base + e], pi[base + e],
                        d0, d1, d2, d3, d4, i0, i1, i2, i3, i4);
    }
    lD[t * 5] = d0; lD[t * 5 + 1] = d1; lD[t * 5 + 2] = d2; lD[t * 5 + 3] = d3; lD[t * 5 + 4] = d4;
    lI[t * 5] = i0; lI[t * 5 + 1] = i1; lI[t * 5 + 2] = i2; lI[t * 5 + 3] = i3; lI[t * 5 + 4] = i4;
    __syncthreads();
    if (t < 32) {
        d0 = d1 = d2 = d3 = d4 = 3.0e38f; i0 = i1 = i2 = i3 = i4 = 0;
        for (int s = 0; s < 8; s++) {
            const int base = (t * 8 + s) * 5;
            #pragma unroll
            for (int e = 0; e < 5; e++)
                topk_insert(lD[base + e], lI[base + e],
                            d0, d1, d2, d3, d4, i0, i1, i2, i3, i4);
        }
        sD[t * 5] = d0; sD[t * 5 + 1] = d1; sD[t * 5 + 2] = d2; sD[t * 5 + 3] = d3; sD[t * 5 + 4] = d4;
        sI[t * 5] = i0; sI[t * 5 + 1] = i1; sI[t * 5 + 2] = i2; sI[t * 5 + 3] = i3; sI[t * 5 + 4] = i4;
    }
    __syncthreads();
    if (t == 0) {   // approx top-10 candidate set
        float dd[10]; int ii[10];
        #pragma unroll
        for (int j = 0; j < 10; j++) { dd[j] = 3.0e38f; ii[j] = 0; }
        for (int s2 = 0; s2 < 160; s2++) {
            const float v = sD[s2]; const int ix = sI[s2];
            if (v < dd[9]) {
                int j = 9;
                while (j > 0 && dd[j - 1] > v) { dd[j] = dd[j - 1]; ii[j] = ii[j - 1]; j--; }
                dd[j] = v; ii[j] = ix;
            }
        }
        #pragma unroll
        for (int j = 0; j < 10; j++) exi[j] = ii[j];
    }
    __syncthreads();
    if (t < 80) {   // exact fp32 sq for 10 candidates, 8 lanes each
        const int cand = t >> 3, seg = t & 7;
        const int row = exi[cand];
        const float4* rp = (const float4*)(reps + (size_t)row * DK) + seg * 4;
        float s = 0.f;
        #pragma unroll
        for (int q = 0; q < 4; q++) {
            const float4 v = rp[q];
            const int k0 = seg * 16 + q * 4;
            s += v.x * v.x + brt[(k0 + 0) * BATCH + b] * v.x;
            s += v.y * v.y + brt[(k0 + 1) * BATCH + b] * v.y;
            s += v.z * v.z + brt[(k0 + 2) * BATCH + b] * v.z;
            s += v.w * v.w + brt[(k0 + 3) * BATCH + b] * v.w;
        }
        s += __shfl_xor(s, 1); s += __shfl_xor(s, 2); s += __shfl_xor(s, 4);
        if ((t & 7) == 0) exq[cand] = s;
    }
    __syncthreads();
    if (t == 0) {
        const float bn = brnorm[b];
        float dd[10];
        #pragma unroll
        for (int j = 0; j < 10; j++) dd[j] = sqrtf(fmaxf(exq[j] + bn, 1e-12f));
        float dist5[5]; int idx5[5];
        bool used[10] = {false,false,false,false,false,false,false,false,false,false};
        for (int e = 0; e < 5; e++) {
            int am = -1; float mv = 3.0e38f;
            for (int j = 0; j < 10; j++)
                if (!used[j] && dd[j] < mv) { mv = dd[j]; am = j; }
            used[am] = true; dist5[e] = mv; idx5[e] = exi[am];
        }
        const float dmin = dist5[0];
        float w[5], wsum = 0.f;
        #pragma unroll
        for (int e = 0; e < 5; e++) { w[e] = expf(dmin - dist5[e]); wsum += w[e]; }
        const float inv = 1.0f / wsum;
        for (int a = 0; a < ACT; a++) {
            float o = 0.f;
            #pragma unroll
            for (int e = 0; e < 5; e++)
                o = fmaf(w[e], actions[(size_t)idx5[e] * ACT + a], o);
            out[b * ACT + a] = o * inv;
        }
    }
}

extern "C" void kernel_launch(void* const* d_in, const int* in_sizes, int n_in,
                              void* d_out, int out_size, void* d_ws, size_t ws_size,
                              hipStream_t stream)
{
    (void)in_sizes; (void)n_in; (void)out_size;
    const float* x       = (const float*)d_in[0];
    const float* W       = (const float*)d_in[1];
    const float* be      = (const float*)d_in[2];
    const float* reps    = (const float*)d_in[3];
    const float* actions = (const float*)d_in[4];
    // d_in[5] = k (always 5; structural)

    float* ws     = (float*)d_ws;
    float* brept  = ws;            // 4096 floats (brep_t[k][b], pre-scaled -2)
    float* brnorm = ws + 4096;     // 32 floats
    float* pd     = ws + 4224;     // G*32*5 floats

    int G = GDEF;
    {
        const size_t avail_f = ws_size / 4;
        if (avail_f < 4224 + (size_t)G * 320) {
            long fit = ((long)avail_f - 4224) / 320;
            G = (fit < 1) ? 1 : (int)fit;
            if (G > GDEF) G = GDEF;
        }
    }
    int* pi = (int*)(pd + (size_t)G * BATCH * 5);

    encoder_kernel  <<<32, 256, 0, stream>>>(x, W, be, brept, brnorm);
    dist_topk_kernel<<<G,  256, 0, stream>>>(reps, brept, pd, pi);
    final_kernel    <<<32, 256, 0, stream>>>(pd, pi, brnorm, actions, reps, brept,
                                             (float*)d_out, G);
}